// Round 7
// baseline (200.575 us; speedup 1.0000x reference)
//
#include <hip/hip_runtime.h>

typedef short bf16x8 __attribute__((ext_vector_type(8)));
typedef float f32x4 __attribute__((ext_vector_type(4)));
typedef float float4v __attribute__((ext_vector_type(4)));
typedef short short4v __attribute__((ext_vector_type(4)));
typedef unsigned uint2v __attribute__((ext_vector_type(2)));

#define B_ 4
#define S_ 2048
#define E_ 1024
#define H_ 16
#define D_ 64
#define M_ (B_*S_)      // 8192
#define N1_ (3*E_)      // 3072

// fp32 -> bf16 round-to-nearest-even
__device__ inline short f2bs(float f) {
    unsigned u = __builtin_bit_cast(unsigned, f);
    unsigned r = u + 0x7fffu + ((u >> 16) & 1u);
    return (short)(r >> 16);
}
__device__ inline float exp2a(float x) {
    float r; asm("v_exp_f32 %0, %1" : "=v"(r) : "v"(x)); return r;
}
__device__ inline unsigned cvtpk(float a, float b) {
    unsigned r; asm("v_cvt_pk_bf16_f32 %0, %1, %2" : "=v"(r) : "v"(a), "v"(b)); return r;
}

__device__ inline const __attribute__((address_space(1))) void* gas(const void* p) {
    return (const __attribute__((address_space(1))) void*)p;
}
__device__ inline __attribute__((address_space(3))) void* las(void* p) {
    return (__attribute__((address_space(3))) void*)p;
}

// ---------------- elementwise fp32 -> bf16 ----------------
__global__ void convert_f32_bf16(const float* __restrict__ in, short* __restrict__ out, int n) {
    int tid = blockIdx.x * blockDim.x + threadIdx.x;
    int stride = gridDim.x * blockDim.x;
    for (int i = tid * 4; i < n; i += stride * 4) {
        float4v v = *(const float4v*)&in[i];
        short4v o;
        o[0] = f2bs(v[0]); o[1] = f2bs(v[1]); o[2] = f2bs(v[2]); o[3] = f2bs(v[3]);
        *(short4v*)&out[i] = o;
    }
}

// ---------------- tiled transpose + convert ----------------
__global__ void transpose_convert(const float* __restrict__ in, short* __restrict__ out,
                                  int rows, int cols) {
    __shared__ float t[32][33];
    int bx = blockIdx.x * 32;
    int by = blockIdx.y * 32;
    int tx = threadIdx.x, ty = threadIdx.y;  // (32, 8)
#pragma unroll
    for (int i = 0; i < 4; ++i)
        t[ty + i * 8][tx] = in[(size_t)(by + ty + i * 8) * cols + bx + tx];
    __syncthreads();
#pragma unroll
    for (int i = 0; i < 4; ++i)
        out[(size_t)(bx + ty + i * 8) * rows + by + tx] = f2bs(t[tx][ty + i * 8]);
}

// ================= 256x256 8-phase GEMM (QKV) =================
#define MFMA16(Q) \
    _Pragma("unroll") for (int mf = 0; mf < 2; ++mf) \
    _Pragma("unroll") for (int nf = 0; nf < 4; ++nf) { \
        acc[(Q)*2+mf][nf] = __builtin_amdgcn_mfma_f32_16x16x32_bf16(af[mf][0], bfrag[nf][0], acc[(Q)*2+mf][nf], 0, 0, 0); \
        acc[(Q)*2+mf][nf] = __builtin_amdgcn_mfma_f32_16x16x32_bf16(af[mf][1], bfrag[nf][1], acc[(Q)*2+mf][nf], 0, 0, 0); \
    }

#define PHASE(Q, STAGE_STMT, WAITV) do { \
    bf16x8 af[2][2]; \
    _Pragma("unroll") for (int mf = 0; mf < 2; ++mf) \
    _Pragma("unroll") for (int ks = 0; ks < 2; ++ks) { \
        int r = (Q)*32 + mf*16 + li; \
        af[mf][ks] = *(const bf16x8*)(lA + r*128 + ((ks*64 + g*16) ^ ((r & 7) << 4))); \
    } \
    STAGE_STMT; \
    __builtin_amdgcn_s_barrier(); \
    asm volatile("s_waitcnt lgkmcnt(0)" ::: "memory"); \
    __builtin_amdgcn_sched_barrier(0); \
    __builtin_amdgcn_s_setprio(1); \
    MFMA16(Q); \
    __builtin_amdgcn_s_setprio(0); \
    WAITV; \
    __builtin_amdgcn_s_barrier(); \
} while (0)

#define VMW(n) asm volatile("s_waitcnt vmcnt(" #n ")" ::: "memory")
#define NOP_ ((void)0)

__global__ __launch_bounds__(512, 2) void gemm256_qkv(
    const short* __restrict__ A, const short* __restrict__ Bt,
    const float* __restrict__ bias,
    short* __restrict__ Qb, short* __restrict__ Kb, short* __restrict__ Vt) {
    __shared__ __attribute__((aligned(16))) short lds[2][2][2][8192];  // [buf][A/B][half][128x64]
    const int tid = threadIdx.x;
    const int lane = tid & 63;
    const int wid = tid >> 6;
    const int li = lane & 15, g = lane >> 4;
    const int wr = wid >> 2, wc = wid & 3;
    const int Kdim = E_;       // 1024
    const int NT = Kdim >> 6;  // 16 K-tiles

    // bijective XCD swizzle: nwg=384, 384/8=48
    const int id = blockIdx.x;
    const int swz = (id & 7) * 48 + (id >> 3);
    const int bx = swz % 12, by = swz / 12;
    const int row0 = by * 256, col0 = bx * 256;

    // staging lane geometry: linear LDS dest, inverse-swizzled global src.
    const int rstage = wid * 8 + (lane >> 3);
    const int cstage = (((lane & 7) ^ ((lane >> 3) & 7)) << 4);

    auto stageA = [&](int buf, int kt, int seg) {
#pragma unroll
        for (int h = 0; h < 2; ++h) {
            const char* src = (const char*)A +
                ((size_t)(row0 + h * 128 + seg * 64 + rstage) * Kdim + kt * 64) * 2 + cstage;
            char* dst = (char*)&lds[buf][0][h][0] + seg * 8192 + wid * 1024;
            __builtin_amdgcn_global_load_lds(gas(src), las(dst), 16, 0, 0);
        }
    };
    auto stageB = [&](int buf, int kt, int h) {
#pragma unroll
        for (int seg = 0; seg < 2; ++seg) {
            const char* src = (const char*)Bt +
                ((size_t)(col0 + h * 128 + seg * 64 + rstage) * Kdim + kt * 64) * 2 + cstage;
            char* dst = (char*)&lds[buf][1][h][0] + seg * 8192 + wid * 1024;
            __builtin_amdgcn_global_load_lds(gas(src), las(dst), 16, 0, 0);
        }
    };

    f32x4 acc[8][4];
#pragma unroll
    for (int m = 0; m < 8; ++m)
#pragma unroll
        for (int n = 0; n < 4; ++n) acc[m][n] = (f32x4){0.f, 0.f, 0.f, 0.f};

    stageB(0, 0, 0);
    stageB(0, 0, 1);
    stageA(0, 0, 0);
    stageA(0, 0, 1);
    asm volatile("s_waitcnt vmcnt(0)" ::: "memory");
    __syncthreads();

    const int bc = (wc & 1) * 64;
    for (int t = 0; t < NT; ++t) {
        const int cur = t & 1;
        const int nb = cur ^ 1;
        const int tn = t + 1;
        const bool st = (tn < NT);
        const char* lA = (const char*)&lds[cur][0][wr][0];
        const char* lB = (const char*)&lds[cur][1][wc >> 1][0];

        bf16x8 bfrag[4][2];
#pragma unroll
        for (int nf = 0; nf < 4; ++nf)
#pragma unroll
            for (int ks = 0; ks < 2; ++ks) {
                int r = bc + nf * 16 + li;
                bfrag[nf][ks] = *(const bf16x8*)(lB + r * 128 + ((ks * 64 + g * 16) ^ ((r & 7) << 4)));
            }
        if (st) {
            PHASE(0, stageB(nb, tn, 0), NOP_);
            PHASE(1, stageB(nb, tn, 1), VMW(4));
            PHASE(2, stageA(nb, tn, 0), NOP_);
            PHASE(3, stageA(nb, tn, 1), VMW(2));
        } else {
            PHASE(0, NOP_, NOP_);
            PHASE(1, NOP_, VMW(0));
            PHASE(2, NOP_, NOP_);
            PHASE(3, NOP_, NOP_);
        }
    }

    // ---- epilogue (C layout: col = lane&15, row = (lane>>4)*4 + j) ----
    if (col0 < 2048) {
        short* Dst = (col0 < 1024) ? Qb : Kb;
#pragma unroll
        for (int nf = 0; nf < 4; ++nf) {
            int ncolg = col0 + wc * 64 + nf * 16 + li;
            float bv = bias[ncolg];
            int ncol = ncolg & 1023;
#pragma unroll
            for (int mi = 0; mi < 8; ++mi) {
                int rbase = row0 + wr * 128 + mi * 16 + 4 * g;
#pragma unroll
                for (int j = 0; j < 4; ++j)
                    Dst[(size_t)(rbase + j) * E_ + ncol] = f2bs(acc[mi][nf][j] + bv);
            }
        }
    } else {
#pragma unroll
        for (int nf = 0; nf < 4; ++nf) {
            int ncolg = col0 + wc * 64 + nf * 16 + li;
            float bv = bias[ncolg];
            int rem = ncolg & 1023;
            int h = rem >> 6, d = rem & 63;
#pragma unroll
            for (int mi = 0; mi < 8; ++mi) {
                int s0 = row0 + wr * 128 + mi * 16 + 4 * g;
                int bb2 = s0 >> 11;
                int ss = s0 & 2047;
                uint2v p;
                p[0] = cvtpk(acc[mi][nf][0] + bv, acc[mi][nf][1] + bv);
                p[1] = cvtpk(acc[mi][nf][2] + bv, acc[mi][nf][3] + bv);
                *(uint2v*)&Vt[((size_t)(bb2 * H_ + h) * D_ + d) * S_ + ss] = p;
            }
        }
    }
}

// ---------------- bf16 GEMM, 128x128 tile (out-proj) ----------------
__global__ __launch_bounds__(256, 2) void gemm_bt_out(
    const short* __restrict__ A, const short* __restrict__ Bt,
    const float* __restrict__ bias, float* __restrict__ Cf,
    int Kdim, int Ndim) {
    __shared__ __attribute__((aligned(16))) short As[128 * 32];
    __shared__ __attribute__((aligned(16))) short Bs[128 * 32];
    const int lane = threadIdx.x & 63;
    const int wv = threadIdx.x >> 6;
    const int row0 = blockIdx.y * 128;
    const int col0 = blockIdx.x * 128;
    const int wr = (wv >> 1) * 64;
    const int wc = (wv & 1) * 64;
    const int li = lane & 15;
    const int g = lane >> 4;
    const int lr = lane >> 2;
    const int lk = (lane & 3) * 8;

    f32x4 acc[4][4];
#pragma unroll
    for (int m = 0; m < 4; ++m)
#pragma unroll
        for (int n = 0; n < 4; ++n) acc[m][n] = (f32x4){0.f, 0.f, 0.f, 0.f};

    for (int k0 = 0; k0 < Kdim; k0 += 32) {
#pragma unroll
        for (int i = 0; i < 2; ++i) {
            int cc = wv * 2 + i;
            const short* ga = A + (size_t)(row0 + cc * 16 + lr) * Kdim + k0 + lk;
            __builtin_amdgcn_global_load_lds(gas(ga), las(&As[cc * 512]), 16, 0, 0);
            const short* gb = Bt + (size_t)(col0 + cc * 16 + lr) * Kdim + k0 + lk;
            __builtin_amdgcn_global_load_lds(gas(gb), las(&Bs[cc * 512]), 16, 0, 0);
        }
        __syncthreads();
        bf16x8 af[4], bfr[4];
#pragma unroll
        for (int m = 0; m < 4; ++m) af[m] = *(const bf16x8*)&As[(wr + 16 * m + li) * 32 + g * 8];
#pragma unroll
        for (int n = 0; n < 4; ++n) bfr[n] = *(const bf16x8*)&Bs[(wc + 16 * n + li) * 32 + g * 8];
#pragma unroll
        for (int m = 0; m < 4; ++m)
#pragma unroll
            for (int n = 0; n < 4; ++n)
                acc[m][n] = __builtin_amdgcn_mfma_f32_16x16x32_bf16(af[m], bfr[n], acc[m][n], 0, 0, 0);
        __syncthreads();
    }

#pragma unroll
    for (int n = 0; n < 4; ++n) {
        int ncol = col0 + wc + 16 * n + li;
        float bv = bias[ncol];
#pragma unroll
        for (int m = 0; m < 4; ++m) {
            int rbase = row0 + wr + 16 * m + 4 * g;
#pragma unroll
            for (int j = 0; j < 4; ++j)
                Cf[(size_t)(rbase + j) * Ndim + ncol] = acc[m][n][j] + bv;
        }
    }
}

// ---------------- causal flash attention v5: full-occupancy grid ----------------
// 1024 blocks x 512 threads = 8192 waves = 32 waves/CU (100% occupancy headroom).
// Each block owns ONE 128-row q-tile; qt descending (heavy first), heads grouped
// per XCD. Single-buffered K/V staging (32KB LDS -> 4 blocks/CU fit).
__global__ __launch_bounds__(512, 4) void attn_kernel(
    const short* __restrict__ Qb, const short* __restrict__ Kb,
    const short* __restrict__ Vt, short* __restrict__ Ob) {
    __shared__ __attribute__((aligned(16))) short Kl[4096];       // 8 KB
    __shared__ __attribute__((aligned(16))) short Vl[4096];       // 8 KB
    __shared__ __attribute__((aligned(16))) short Plds[8][1024];  // 16 KB
    const int lane = threadIdx.x & 63;
    const int wv = threadIdx.x >> 6;
    const int li = lane & 15;
    const int g = lane >> 4;
    // id -> xcd (round-robin match), qt heavy-first, head within xcd group
    const int id = blockIdx.x;
    const int xcd = id & 7;
    const int r = id >> 3;                 // 0..127
    const int qt = 15 - (r >> 3);          // 15..0
    const int bh = xcd * 8 + (r & 7);      // 0..63
    const int bb = bh >> 4, hh = bh & 15;
    const short* Qh = Qb + (size_t)bb * (S_ * E_) + hh * 64;
    const short* Kh = Kb + (size_t)bb * (S_ * E_) + hh * 64;
    const short* Vh = Vt + (size_t)bh * (D_ * S_);
    const float CEXP = 0.18033688011112042f;  // (1/8)*log2(e)
    bf16x8 ONES;
#pragma unroll
    for (int i = 0; i < 8; ++i) ONES[i] = (short)0x3F80;

    const int r8 = lane >> 3;
    const int c16 = ((lane & 7) ^ r8) << 4;
    const int strow = wv * 8 + r8;
    char* Pb = (char*)&Plds[wv][0];
    const int lsw = (li & 7) << 4;

    const int q0 = qt * 128 + wv * 16;
    bf16x8 qa[2];
#pragma unroll
    for (int c = 0; c < 2; ++c)
        qa[c] = *(const bf16x8*)&Qh[(size_t)(q0 + li) * E_ + c * 32 + g * 8];
    f32x4 acc[4];
    f32x4 lsum = (f32x4){0.f, 0.f, 0.f, 0.f};
#pragma unroll
    for (int dc = 0; dc < 4; ++dc) acc[dc] = (f32x4){0.f, 0.f, 0.f, 0.f};
    float mrow[4], mrowC[4];
#pragma unroll
    for (int j = 0; j < 4; ++j) { mrow[j] = -3e38f; mrowC[j] = 0.f; }

    const int nw = (q0 + 79) >> 6;         // k-tiles this wave computes
    const int nt = (qt * 128 + 191) >> 6;  // k-tiles staged by block

    for (int it = 0; it < nt; ++it) {
        const int kt0 = it * 64;
        {
            const char* gk = (const char*)(Kh + (size_t)(kt0 + strow) * E_) + c16;
            __builtin_amdgcn_global_load_lds(gas(gk), las((char*)Kl + wv * 1024), 16, 0, 0);
            const char* gv = (const char*)Vh + (size_t)strow * (S_ * 2) + (size_t)kt0 * 2 + c16;
            __builtin_amdgcn_global_load_lds(gas(gv), las((char*)Vl + wv * 1024), 16, 0, 0);
        }
        __syncthreads();
        if (it < nw) {
            const bool bmask = (it == nw - 1);
            bf16x8 kf[4][2];
#pragma unroll
            for (int kc = 0; kc < 4; ++kc)
#pragma unroll
                for (int c = 0; c < 2; ++c)
                    kf[kc][c] = *(const bf16x8*)((const char*)Kl + (kc * 16 + li) * 128 +
                                                 ((c * 64 + g * 16) ^ lsw));
            f32x4 sc4[4];
#pragma unroll
            for (int kc = 0; kc < 4; ++kc) {
                f32x4 z = (f32x4){0.f, 0.f, 0.f, 0.f};
                z = __builtin_amdgcn_mfma_f32_16x16x32_bf16(qa[0], kf[kc][0], z, 0, 0, 0);
                z = __builtin_amdgcn_mfma_f32_16x16x32_bf16(qa[1], kf[kc][1], z, 0, 0, 0);
                sc4[kc] = z;
            }
            if (bmask) {
#pragma unroll
                for (int kc = 0; kc < 4; ++kc) {
                    int key = kt0 + kc * 16 + li;
#pragma unroll
                    for (int j = 0; j < 4; ++j) {
                        int qr = q0 + 4 * g + j;
                        sc4[kc][j] = (key > qr) ? -3e38f : sc4[kc][j];
                    }
                }
            }
            float tmax[4];
#pragma unroll
            for (int j = 0; j < 4; ++j)
                tmax[j] = fmaxf(fmaxf(sc4[0][j], sc4[1][j]), fmaxf(sc4[2][j], sc4[3][j]));
#pragma unroll
            for (int msk = 1; msk < 16; msk <<= 1)
#pragma unroll
                for (int j = 0; j < 4; ++j)
                    tmax[j] = fmaxf(tmax[j], __shfl_xor(tmax[j], msk, 64));
            bool need = (tmax[0] > mrow[0]) | (tmax[1] > mrow[1]) |
                        (tmax[2] > mrow[2]) | (tmax[3] > mrow[3]);
            if (__ballot((int)need) != 0ull) {
#pragma unroll
                for (int j = 0; j < 4; ++j) {
                    float mn = fmaxf(mrow[j], tmax[j]);
                    float sf = exp2a((mrow[j] - mn) * CEXP);
                    mrow[j] = mn;
                    mrowC[j] = mn * CEXP;
                    lsum[j] *= sf;
#pragma unroll
                    for (int dc = 0; dc < 4; ++dc) acc[dc][j] *= sf;
                }
            }
#pragma unroll
            for (int j = 0; j < 4; ++j) {
                const int rowb = (4 * g + j) * 128;
                const int rx = ((4 * g + j) & 7) << 4;
#pragma unroll
                for (int kp = 0; kp < 2; ++kp) {
                    float p0 = exp2a(fmaf(sc4[2 * kp][j], CEXP, -mrowC[j]));
                    float p1 = exp2a(fmaf(sc4[2 * kp + 1][j], CEXP, -mrowC[j]));
                    unsigned u = cvtpk(p0, p1);
                    *(short*)(Pb + rowb + ((kp * 64 + li * 2) ^ rx)) = (short)u;
                    *(short*)(Pb + rowb + ((kp * 64 + 32 + li * 2) ^ rx)) = (short)(u >> 16);
                }
            }
            bf16x8 vf[4][2];
#pragma unroll
            for (int dc = 0; dc < 4; ++dc)
#pragma unroll
                for (int c = 0; c < 2; ++c)
                    vf[dc][c] = *(const bf16x8*)((const char*)Vl + (dc * 16 + li) * 128 +
                                                 ((c * 64 + g * 16) ^ lsw));
            asm volatile("s_waitcnt lgkmcnt(0)" ::: "memory");
            __builtin_amdgcn_sched_barrier(0);
            bf16x8 pa[2];
#pragma unroll
            for (int c = 0; c < 2; ++c)
                pa[c] = *(const bf16x8*)(Pb + li * 128 + ((c * 64 + g * 16) ^ lsw));
#pragma unroll
            for (int dc = 0; dc < 4; ++dc) {
                acc[dc] = __builtin_amdgcn_mfma_f32_16x16x32_bf16(pa[0], vf[dc][0], acc[dc], 0, 0, 0);
                acc[dc] = __builtin_amdgcn_mfma_f32_16x16x32_bf16(pa[1], vf[dc][1], acc[dc], 0, 0, 0);
            }
            lsum = __builtin_amdgcn_mfma_f32_16x16x32_bf16(pa[0], ONES, lsum, 0, 0, 0);
            lsum = __builtin_amdgcn_mfma_f32_16x16x32_bf16(pa[1], ONES, lsum, 0, 0, 0);
        }
        __syncthreads();
    }

    float rl[4];
#pragma unroll
    for (int j = 0; j < 4; ++j) rl[j] = __builtin_amdgcn_rcpf(lsum[j]);
#pragma unroll
    for (int dc = 0; dc < 4; ++dc)
#pragma unroll
        for (int j = 0; j < 4; ++j) {
            int sr = q0 + 4 * g + j;
            Ob[((size_t)(bb * S_ + sr)) * E_ + hh * 64 + dc * 16 + li] = f2bs(acc[dc][j] * rl[j]);
        }
}

extern "C" void kernel_launch(void* const* d_in, const int* in_sizes, int n_in,
                              void* d_out, int out_size, void* d_ws, size_t ws_size,
                              hipStream_t stream) {
    const float* x      = (const float*)d_in[0];
    const float* w_attn = (const float*)d_in[1];
    const float* b_attn = (const float*)d_in[2];
    const float* w_out  = (const float*)d_in[3];
    const float* b_out  = (const float*)d_in[4];
    float* out = (float*)d_out;

    char* ws = (char*)d_ws;
    short* Xbf  = (short*)(ws);                       // 16 MB (reused as attn output)
    short* Wat  = (short*)(ws + (16ull << 20));       // 6 MB  [3072][1024]
    short* Wot  = (short*)(ws + (22ull << 20));       // 2 MB  [1024][1024]
    short* Qb   = (short*)(ws + (24ull << 20));       // 16 MB flat [8192][1024]
    short* Kb   = (short*)(ws + (40ull << 20));       // 16 MB flat [8192][1024]
    short* Vt   = (short*)(ws + (56ull << 20));       // 16 MB [B,H,D,S]
    short* Obuf = Xbf;

    convert_f32_bf16<<<2048, 256, 0, stream>>>(x, Xbf, M_ * E_);
    transpose_convert<<<dim3(N1_ / 32, E_ / 32), dim3(32, 8), 0, stream>>>(w_attn, Wat, E_, N1_);
    transpose_convert<<<dim3(E_ / 32, E_ / 32), dim3(32, 8), 0, stream>>>(w_out, Wot, E_, E_);

    gemm256_qkv<<<384, 512, 0, stream>>>(Xbf, Wat, b_attn, Qb, Kb, Vt);

    attn_kernel<<<1024, 512, 0, stream>>>(Qb, Kb, Vt, Obuf);

    gemm_bt_out<<<dim3(E_ / 128, M_ / 128), 256, 0, stream>>>(
        Obuf, Wot, b_out, out, E_, E_);
}

// Round 8
// 184.300 us; speedup vs baseline: 1.0883x; 1.0883x over previous
//
#include <hip/hip_runtime.h>

typedef short bf16x8 __attribute__((ext_vector_type(8)));
typedef float f32x4 __attribute__((ext_vector_type(4)));
typedef float f32x16 __attribute__((ext_vector_type(16)));
typedef float float4v __attribute__((ext_vector_type(4)));
typedef short short4v __attribute__((ext_vector_type(4)));
typedef unsigned uint2v __attribute__((ext_vector_type(2)));
typedef unsigned uint4v __attribute__((ext_vector_type(4)));

#define B_ 4
#define S_ 2048
#define E_ 1024
#define H_ 16
#define D_ 64
#define M_ (B_*S_)      // 8192
#define N1_ (3*E_)      // 3072

// fp32 -> bf16 round-to-nearest-even
__device__ inline short f2bs(float f) {
    unsigned u = __builtin_bit_cast(unsigned, f);
    unsigned r = u + 0x7fffu + ((u >> 16) & 1u);
    return (short)(r >> 16);
}
__device__ inline float exp2a(float x) {
    float r; asm("v_exp_f32 %0, %1" : "=v"(r) : "v"(x)); return r;
}
__device__ inline unsigned cvtpk(float a, float b) {
    unsigned r; asm("v_cvt_pk_bf16_f32 %0, %1, %2" : "=v"(r) : "v"(a), "v"(b)); return r;
}

__device__ inline const __attribute__((address_space(1))) void* gas(const void* p) {
    return (const __attribute__((address_space(1))) void*)p;
}
__device__ inline __attribute__((address_space(3))) void* las(void* p) {
    return (__attribute__((address_space(3))) void*)p;
}

// ---------------- elementwise fp32 -> bf16 ----------------
__global__ void convert_f32_bf16(const float* __restrict__ in, short* __restrict__ out, int n) {
    int tid = blockIdx.x * blockDim.x + threadIdx.x;
    int stride = gridDim.x * blockDim.x;
    for (int i = tid * 4; i < n; i += stride * 4) {
        float4v v = *(const float4v*)&in[i];
        short4v o;
        o[0] = f2bs(v[0]); o[1] = f2bs(v[1]); o[2] = f2bs(v[2]); o[3] = f2bs(v[3]);
        *(short4v*)&out[i] = o;
    }
}

// ---------------- tiled transpose + convert ----------------
__global__ void transpose_convert(const float* __restrict__ in, short* __restrict__ out,
                                  int rows, int cols) {
    __shared__ float t[32][33];
    int bx = blockIdx.x * 32;
    int by = blockIdx.y * 32;
    int tx = threadIdx.x, ty = threadIdx.y;  // (32, 8)
#pragma unroll
    for (int i = 0; i < 4; ++i)
        t[ty + i * 8][tx] = in[(size_t)(by + ty + i * 8) * cols + bx + tx];
    __syncthreads();
#pragma unroll
    for (int i = 0; i < 4; ++i)
        out[(size_t)(bx + ty + i * 8) * rows + by + tx] = f2bs(t[tx][ty + i * 8]);
}

// ================= 256x256 8-phase GEMM (QKV) =================
#define MFMA16(Q) \
    _Pragma("unroll") for (int mf = 0; mf < 2; ++mf) \
    _Pragma("unroll") for (int nf = 0; nf < 4; ++nf) { \
        acc[(Q)*2+mf][nf] = __builtin_amdgcn_mfma_f32_16x16x32_bf16(af[mf][0], bfrag[nf][0], acc[(Q)*2+mf][nf], 0, 0, 0); \
        acc[(Q)*2+mf][nf] = __builtin_amdgcn_mfma_f32_16x16x32_bf16(af[mf][1], bfrag[nf][1], acc[(Q)*2+mf][nf], 0, 0, 0); \
    }

#define PHASE(Q, STAGE_STMT, WAITV) do { \
    bf16x8 af[2][2]; \
    _Pragma("unroll") for (int mf = 0; mf < 2; ++mf) \
    _Pragma("unroll") for (int ks = 0; ks < 2; ++ks) { \
        int r = (Q)*32 + mf*16 + li; \
        af[mf][ks] = *(const bf16x8*)(lA + r*128 + ((ks*64 + g*16) ^ ((r & 7) << 4))); \
    } \
    STAGE_STMT; \
    __builtin_amdgcn_s_barrier(); \
    asm volatile("s_waitcnt lgkmcnt(0)" ::: "memory"); \
    __builtin_amdgcn_sched_barrier(0); \
    __builtin_amdgcn_s_setprio(1); \
    MFMA16(Q); \
    __builtin_amdgcn_s_setprio(0); \
    WAITV; \
    __builtin_amdgcn_s_barrier(); \
} while (0)

#define VMW(n) asm volatile("s_waitcnt vmcnt(" #n ")" ::: "memory")
#define NOP_ ((void)0)

__global__ __launch_bounds__(512, 2) void gemm256_qkv(
    const short* __restrict__ A, const short* __restrict__ Bt,
    const float* __restrict__ bias,
    short* __restrict__ Qb, short* __restrict__ Kb, short* __restrict__ Vt) {
    __shared__ __attribute__((aligned(16))) short lds[2][2][2][8192];  // [buf][A/B][half][128x64]
    const int tid = threadIdx.x;
    const int lane = tid & 63;
    const int wid = tid >> 6;
    const int li = lane & 15, g = lane >> 4;
    const int wr = wid >> 2, wc = wid & 3;
    const int Kdim = E_;       // 1024
    const int NT = Kdim >> 6;  // 16 K-tiles

    // bijective XCD swizzle: nwg=384, 384/8=48
    const int id = blockIdx.x;
    const int swz = (id & 7) * 48 + (id >> 3);
    const int bx = swz % 12, by = swz / 12;
    const int row0 = by * 256, col0 = bx * 256;

    // staging lane geometry: linear LDS dest, inverse-swizzled global src.
    const int rstage = wid * 8 + (lane >> 3);
    const int cstage = (((lane & 7) ^ ((lane >> 3) & 7)) << 4);

    auto stageA = [&](int buf, int kt, int seg) {
#pragma unroll
        for (int h = 0; h < 2; ++h) {
            const char* src = (const char*)A +
                ((size_t)(row0 + h * 128 + seg * 64 + rstage) * Kdim + kt * 64) * 2 + cstage;
            char* dst = (char*)&lds[buf][0][h][0] + seg * 8192 + wid * 1024;
            __builtin_amdgcn_global_load_lds(gas(src), las(dst), 16, 0, 0);
        }
    };
    auto stageB = [&](int buf, int kt, int h) {
#pragma unroll
        for (int seg = 0; seg < 2; ++seg) {
            const char* src = (const char*)Bt +
                ((size_t)(col0 + h * 128 + seg * 64 + rstage) * Kdim + kt * 64) * 2 + cstage;
            char* dst = (char*)&lds[buf][1][h][0] + seg * 8192 + wid * 1024;
            __builtin_amdgcn_global_load_lds(gas(src), las(dst), 16, 0, 0);
        }
    };

    f32x4 acc[8][4];
#pragma unroll
    for (int m = 0; m < 8; ++m)
#pragma unroll
        for (int n = 0; n < 4; ++n) acc[m][n] = (f32x4){0.f, 0.f, 0.f, 0.f};

    stageB(0, 0, 0);
    stageB(0, 0, 1);
    stageA(0, 0, 0);
    stageA(0, 0, 1);
    asm volatile("s_waitcnt vmcnt(0)" ::: "memory");
    __syncthreads();

    const int bc = (wc & 1) * 64;
    for (int t = 0; t < NT; ++t) {
        const int cur = t & 1;
        const int nb = cur ^ 1;
        const int tn = t + 1;
        const bool st = (tn < NT);
        const char* lA = (const char*)&lds[cur][0][wr][0];
        const char* lB = (const char*)&lds[cur][1][wc >> 1][0];

        bf16x8 bfrag[4][2];
#pragma unroll
        for (int nf = 0; nf < 4; ++nf)
#pragma unroll
            for (int ks = 0; ks < 2; ++ks) {
                int r = bc + nf * 16 + li;
                bfrag[nf][ks] = *(const bf16x8*)(lB + r * 128 + ((ks * 64 + g * 16) ^ ((r & 7) << 4)));
            }
        if (st) {
            PHASE(0, stageB(nb, tn, 0), NOP_);
            PHASE(1, stageB(nb, tn, 1), VMW(4));
            PHASE(2, stageA(nb, tn, 0), NOP_);
            PHASE(3, stageA(nb, tn, 1), VMW(2));
        } else {
            PHASE(0, NOP_, NOP_);
            PHASE(1, NOP_, VMW(0));
            PHASE(2, NOP_, NOP_);
            PHASE(3, NOP_, NOP_);
        }
    }

    // ---- epilogue (C layout: col = lane&15, row = (lane>>4)*4 + j) ----
    if (col0 < 2048) {
        short* Dst = (col0 < 1024) ? Qb : Kb;
#pragma unroll
        for (int nf = 0; nf < 4; ++nf) {
            int ncolg = col0 + wc * 64 + nf * 16 + li;
            float bv = bias[ncolg];
            int ncol = ncolg & 1023;
#pragma unroll
            for (int mi = 0; mi < 8; ++mi) {
                int rbase = row0 + wr * 128 + mi * 16 + 4 * g;
#pragma unroll
                for (int j = 0; j < 4; ++j)
                    Dst[(size_t)(rbase + j) * E_ + ncol] = f2bs(acc[mi][nf][j] + bv);
            }
        }
    } else {
#pragma unroll
        for (int nf = 0; nf < 4; ++nf) {
            int ncolg = col0 + wc * 64 + nf * 16 + li;
            float bv = bias[ncolg];
            int rem = ncolg & 1023;
            int h = rem >> 6, d = rem & 63;
#pragma unroll
            for (int mi = 0; mi < 8; ++mi) {
                int s0 = row0 + wr * 128 + mi * 16 + 4 * g;
                int bb2 = s0 >> 11;
                int ss = s0 & 2047;
                uint2v p;
                p[0] = cvtpk(acc[mi][nf][0] + bv, acc[mi][nf][1] + bv);
                p[1] = cvtpk(acc[mi][nf][2] + bv, acc[mi][nf][3] + bv);
                *(uint2v*)&Vt[((size_t)(bb2 * H_ + h) * D_ + d) * S_ + ss] = p;
            }
        }
    }
}

// ---------------- bf16 GEMM, 128x128 tile (out-proj) ----------------
__global__ __launch_bounds__(256, 2) void gemm_bt_out(
    const short* __restrict__ A, const short* __restrict__ Bt,
    const float* __restrict__ bias, float* __restrict__ Cf,
    int Kdim, int Ndim) {
    __shared__ __attribute__((aligned(16))) short As[128 * 32];
    __shared__ __attribute__((aligned(16))) short Bs[128 * 32];
    const int lane = threadIdx.x & 63;
    const int wv = threadIdx.x >> 6;
    const int row0 = blockIdx.y * 128;
    const int col0 = blockIdx.x * 128;
    const int wr = (wv >> 1) * 64;
    const int wc = (wv & 1) * 64;
    const int li = lane & 15;
    const int g = lane >> 4;
    const int lr = lane >> 2;
    const int lk = (lane & 3) * 8;

    f32x4 acc[4][4];
#pragma unroll
    for (int m = 0; m < 4; ++m)
#pragma unroll
        for (int n = 0; n < 4; ++n) acc[m][n] = (f32x4){0.f, 0.f, 0.f, 0.f};

    for (int k0 = 0; k0 < Kdim; k0 += 32) {
#pragma unroll
        for (int i = 0; i < 2; ++i) {
            int cc = wv * 2 + i;
            const short* ga = A + (size_t)(row0 + cc * 16 + lr) * Kdim + k0 + lk;
            __builtin_amdgcn_global_load_lds(gas(ga), las(&As[cc * 512]), 16, 0, 0);
            const short* gb = Bt + (size_t)(col0 + cc * 16 + lr) * Kdim + k0 + lk;
            __builtin_amdgcn_global_load_lds(gas(gb), las(&Bs[cc * 512]), 16, 0, 0);
        }
        __syncthreads();
        bf16x8 af[4], bfr[4];
#pragma unroll
        for (int m = 0; m < 4; ++m) af[m] = *(const bf16x8*)&As[(wr + 16 * m + li) * 32 + g * 8];
#pragma unroll
        for (int n = 0; n < 4; ++n) bfr[n] = *(const bf16x8*)&Bs[(wc + 16 * n + li) * 32 + g * 8];
#pragma unroll
        for (int m = 0; m < 4; ++m)
#pragma unroll
            for (int n = 0; n < 4; ++n)
                acc[m][n] = __builtin_amdgcn_mfma_f32_16x16x32_bf16(af[m], bfr[n], acc[m][n], 0, 0, 0);
        __syncthreads();
    }

#pragma unroll
    for (int n = 0; n < 4; ++n) {
        int ncol = col0 + wc + 16 * n + li;
        float bv = bias[ncol];
#pragma unroll
        for (int m = 0; m < 4; ++m) {
            int rbase = row0 + wr + 16 * m + 4 * g;
#pragma unroll
            for (int j = 0; j < 4; ++j)
                Cf[(size_t)(rbase + j) * Ndim + ncol] = acc[m][n][j] + bv;
        }
    }
}

// ---------------- causal flash attention v6: swapped-QK 32x32, in-register softmax ----------------
// 256 threads = 4 waves x 32 q-rows = 128-row q-tile. Grid 1024 (xcd-pinned, heavy-first).
// S = mfma(K,Q): lane owns q = lane&31, holds 16 of 32 keys (C row = (r&3)+8*(r>>2)+4*hi).
// Softmax lane-local: 15-op tree + 1 shfl_xor(32). P packed via cvt_pk + shfl_xor(32)
// merge into PV B-frags directly (no P LDS, no lgkm fence). PV: A = Vt rows (d), out O^T.
__global__ __launch_bounds__(256, 4) void attn_kernel(
    const short* __restrict__ Qb, const short* __restrict__ Kb,
    const short* __restrict__ Vt, short* __restrict__ Ob) {
    __shared__ __attribute__((aligned(16))) short Kl[4096];  // [64 keys][64 d] 8KB
    __shared__ __attribute__((aligned(16))) short Vl[4096];  // [64 d][64 keys] 8KB
    const int lane = threadIdx.x & 63;
    const int wv = threadIdx.x >> 6;          // 0..3
    const int l31 = lane & 31;
    const int hi = lane >> 5;                 // 0/1
    const int id = blockIdx.x;
    const int xcd = id & 7;
    const int r_ = id >> 3;                   // 0..127
    const int qt = 15 - (r_ >> 3);            // 15..0 heavy-first
    const int bh = xcd * 8 + (r_ & 7);
    const int bb = bh >> 4, hh = bh & 15;
    const short* Qh = Qb + (size_t)bb * (S_ * E_) + hh * 64;
    const short* Kh = Kb + (size_t)bb * (S_ * E_) + hh * 64;
    const short* Vh = Vt + (size_t)bh * (D_ * S_);
    const float CEXP = 0.18033688011112042f;  // (1/8)*log2(e)

    // staging geometry (4 waves stage 32 rows per call; 2 calls per buffer)
    const int rstage = wv * 8 + (lane >> 3);                      // 0..31
    const int cstage = (((lane & 7) ^ ((lane >> 3) & 7)) << 4);   // inverse swizzle

    const int q0w = qt * 128 + wv * 32;
    const int q = q0w + l31;  // this lane's q-row

    // Q fragments (B-operand): lane holds Q[q][c*16 + hi*8 + j]
    bf16x8 qf[4];
#pragma unroll
    for (int c = 0; c < 4; ++c)
        qf[c] = *(const bf16x8*)&Qh[(size_t)q * E_ + c * 16 + hi * 8];

    f32x16 acc[2];
#pragma unroll
    for (int d = 0; d < 2; ++d)
#pragma unroll
        for (int r = 0; r < 16; ++r) acc[d][r] = 0.f;
    float m = -3e38f, mC = 0.f, l = 0.f;

    const int nw = (q0w + 95) >> 6;          // 64-key tiles this wave computes
    const int nt = (qt * 128 + 191) >> 6;    // tiles staged by block

    for (int it = 0; it < nt; ++it) {
        const int kt0 = it * 64;
        // cooperative stage: K [64 keys][64 d], V [64 d][64 keys]
#pragma unroll
        for (int half = 0; half < 2; ++half) {
            const char* gk = (const char*)(Kh + (size_t)(kt0 + half * 32 + rstage) * E_) + cstage;
            __builtin_amdgcn_global_load_lds(gas(gk), las((char*)Kl + half * 4096 + wv * 1024), 16, 0, 0);
            const char* gv = (const char*)Vh + (size_t)(half * 32 + rstage) * (S_ * 2) + (size_t)kt0 * 2 + cstage;
            __builtin_amdgcn_global_load_lds(gas(gv), las((char*)Vl + half * 4096 + wv * 1024), 16, 0, 0);
        }
        __syncthreads();
        if (it < nw) {
#pragma unroll
            for (int s = 0; s < 2; ++s) {
                const int ktl = kt0 + s * 32;
                if (ktl > q0w + 31) continue;  // wave-uniform
                // ---- QK^T (swapped): S[key][q], 4 chained mfma over D=64 ----
                f32x16 sc;
#pragma unroll
                for (int r = 0; r < 16; ++r) sc[r] = 0.f;
#pragma unroll
                for (int c = 0; c < 4; ++c) {
                    const int row = s * 32 + l31;
                    bf16x8 kf = *(const bf16x8*)((const char*)Kl + row * 128 +
                                                 ((c * 32 + hi * 16) ^ ((row & 7) << 4)));
                    sc = __builtin_amdgcn_mfma_f32_32x32x16_bf16(kf, qf[c], sc, 0, 0, 0);
                }
                // ---- causal mask (boundary subtile only) ----
                if (ktl + 31 > q0w) {
                    const int kb = ktl + 4 * hi;
#pragma unroll
                    for (int r = 0; r < 16; ++r) {
                        int key = kb + (r & 3) + 8 * (r >> 2);
                        sc[r] = (key > q) ? -3e38f : sc[r];
                    }
                }
                // ---- row max: local tree + one cross-half shfl ----
                float t0 = fmaxf(sc[0], sc[1]), t1 = fmaxf(sc[2], sc[3]);
                float t2 = fmaxf(sc[4], sc[5]), t3 = fmaxf(sc[6], sc[7]);
                float t4 = fmaxf(sc[8], sc[9]), t5 = fmaxf(sc[10], sc[11]);
                float t6 = fmaxf(sc[12], sc[13]), t7 = fmaxf(sc[14], sc[15]);
                float tm = fmaxf(fmaxf(fmaxf(t0, t1), fmaxf(t2, t3)),
                                 fmaxf(fmaxf(t4, t5), fmaxf(t6, t7)));
                tm = fmaxf(tm, __shfl_xor(tm, 32, 64));
                bool need = (tm > m);
                if (__ballot((int)need) != 0ull) {
                    float mn = fmaxf(m, tm);
                    float sf = exp2a((m - mn) * CEXP);
                    m = mn; mC = mn * CEXP;
                    l *= sf;
#pragma unroll
                    for (int d = 0; d < 2; ++d)
#pragma unroll
                        for (int r = 0; r < 16; ++r) acc[d][r] *= sf;
                }
                // ---- p = exp2(s*C - m*C), local sum + one shfl ----
                float p[16];
#pragma unroll
                for (int r = 0; r < 16; ++r) p[r] = exp2a(fmaf(sc[r], CEXP, -mC));
                float s0 = (p[0] + p[1]) + (p[2] + p[3]);
                float s1 = (p[4] + p[5]) + (p[6] + p[7]);
                float s2 = (p[8] + p[9]) + (p[10] + p[11]);
                float s3 = (p[12] + p[13]) + (p[14] + p[15]);
                float ls = (s0 + s1) + (s2 + s3);
                ls += __shfl_xor(ls, 32, 64);
                l += ls;
                // ---- pack P -> bf16 words, cross-half merge into PV B-frags ----
                unsigned W0 = cvtpk(p[0], p[1]),  W1 = cvtpk(p[2], p[3]);
                unsigned W2 = cvtpk(p[4], p[5]),  W3 = cvtpk(p[6], p[7]);
                unsigned W4 = cvtpk(p[8], p[9]),  W5 = cvtpk(p[10], p[11]);
                unsigned W6 = cvtpk(p[12], p[13]), W7 = cvtpk(p[14], p[15]);
                unsigned xW0 = __shfl_xor(W0, 32, 64), xW1 = __shfl_xor(W1, 32, 64);
                unsigned xW2 = __shfl_xor(W2, 32, 64), xW3 = __shfl_xor(W3, 32, 64);
                unsigned xW4 = __shfl_xor(W4, 32, 64), xW5 = __shfl_xor(W5, 32, 64);
                unsigned xW6 = __shfl_xor(W6, 32, 64), xW7 = __shfl_xor(W7, 32, 64);
                const bool lo = (hi == 0);
                uint4v u1, u2;
                u1[0] = lo ? W0 : xW2;  u1[1] = lo ? W1 : xW3;
                u1[2] = lo ? xW0 : W2;  u1[3] = lo ? xW1 : W3;
                u2[0] = lo ? W4 : xW6;  u2[1] = lo ? W5 : xW7;
                u2[2] = lo ? xW4 : W6;  u2[3] = lo ? xW5 : W7;
                bf16x8 pf1 = __builtin_bit_cast(bf16x8, u1);
                bf16x8 pf2 = __builtin_bit_cast(bf16x8, u2);
                // ---- PV: acc[dblk] += V^T-frag x P-frag ----
#pragma unroll
                for (int db = 0; db < 2; ++db) {
                    const int row = db * 32 + l31;
                    const int rsw = (row & 7) << 4;
                    bf16x8 vf0 = *(const bf16x8*)((const char*)Vl + row * 128 +
                                                  ((s * 64 + hi * 16) ^ rsw));
                    bf16x8 vf1 = *(const bf16x8*)((const char*)Vl + row * 128 +
                                                  ((s * 64 + 32 + hi * 16) ^ rsw));
                    acc[db] = __builtin_amdgcn_mfma_f32_32x32x16_bf16(vf0, pf1, acc[db], 0, 0, 0);
                    acc[db] = __builtin_amdgcn_mfma_f32_32x32x16_bf16(vf1, pf2, acc[db], 0, 0, 0);
                }
            }
        }
        __syncthreads();
    }

    // ---- epilogue: O[q][d] = acc^T / l ; 8B packed stores ----
    float rl = __builtin_amdgcn_rcpf(l);
    short* orow = Ob + ((size_t)(bb * S_ + q)) * E_ + hh * 64;
#pragma unroll
    for (int db = 0; db < 2; ++db)
#pragma unroll
        for (int rb = 0; rb < 4; ++rb) {
            uint2v pk;
            pk[0] = cvtpk(acc[db][rb * 4 + 0] * rl, acc[db][rb * 4 + 1] * rl);
            pk[1] = cvtpk(acc[db][rb * 4 + 2] * rl, acc[db][rb * 4 + 3] * rl);
            *(uint2v*)&orow[db * 32 + rb * 8 + hi * 4] = pk;
        }
}

extern "C" void kernel_launch(void* const* d_in, const int* in_sizes, int n_in,
                              void* d_out, int out_size, void* d_ws, size_t ws_size,
                              hipStream_t stream) {
    const float* x      = (const float*)d_in[0];
    const float* w_attn = (const float*)d_in[1];
    const float* b_attn = (const float*)d_in[2];
    const float* w_out  = (const float*)d_in[3];
    const float* b_out  = (const float*)d_in[4];
    float* out = (float*)d_out;

    char* ws = (char*)d_ws;
    short* Xbf  = (short*)(ws);                       // 16 MB (reused as attn output)
    short* Wat  = (short*)(ws + (16ull << 20));       // 6 MB  [3072][1024]
    short* Wot  = (short*)(ws + (22ull << 20));       // 2 MB  [1024][1024]
    short* Qb   = (short*)(ws + (24ull << 20));       // 16 MB flat [8192][1024]
    short* Kb   = (short*)(ws + (40ull << 20));       // 16 MB flat [8192][1024]
    short* Vt   = (short*)(ws + (56ull << 20));       // 16 MB [B,H,D,S]
    short* Obuf = Xbf;

    convert_f32_bf16<<<2048, 256, 0, stream>>>(x, Xbf, M_ * E_);
    transpose_convert<<<dim3(N1_ / 32, E_ / 32), dim3(32, 8), 0, stream>>>(w_attn, Wat, E_, N1_);
    transpose_convert<<<dim3(E_ / 32, E_ / 32), dim3(32, 8), 0, stream>>>(w_out, Wot, E_, E_);

    gemm256_qkv<<<384, 512, 0, stream>>>(Xbf, Wat, b_attn, Qb, Kb, Vt);

    attn_kernel<<<1024, 256, 0, stream>>>(Qb, Kb, Vt, Obuf);

    gemm_bt_out<<<dim3(E_ / 128, M_ / 128), 256, 0, stream>>>(
        Obuf, Wot, b_out, out, E_, E_);
}

// Round 10
// 177.020 us; speedup vs baseline: 1.1331x; 1.0411x over previous
//
#include <hip/hip_runtime.h>

typedef short bf16x8 __attribute__((ext_vector_type(8)));
typedef float f32x4 __attribute__((ext_vector_type(4)));
typedef float f32x16 __attribute__((ext_vector_type(16)));
typedef float float4v __attribute__((ext_vector_type(4)));
typedef short short4v __attribute__((ext_vector_type(4)));
typedef unsigned uint2v __attribute__((ext_vector_type(2)));
typedef unsigned uint4v __attribute__((ext_vector_type(4)));

#define B_ 4
#define S_ 2048
#define E_ 1024
#define H_ 16
#define D_ 64
#define M_ (B_*S_)      // 8192
#define N1_ (3*E_)      // 3072

// fp32 -> bf16 round-to-nearest-even
__device__ inline short f2bs(float f) {
    unsigned u = __builtin_bit_cast(unsigned, f);
    unsigned r = u + 0x7fffu + ((u >> 16) & 1u);
    return (short)(r >> 16);
}
__device__ inline float exp2a(float x) {
    float r; asm("v_exp_f32 %0, %1" : "=v"(r) : "v"(x)); return r;
}
__device__ inline unsigned cvtpk(float a, float b) {
    unsigned r; asm("v_cvt_pk_bf16_f32 %0, %1, %2" : "=v"(r) : "v"(a), "v"(b)); return r;
}

__device__ inline const __attribute__((address_space(1))) void* gas(const void* p) {
    return (const __attribute__((address_space(1))) void*)p;
}
__device__ inline __attribute__((address_space(3))) void* las(void* p) {
    return (__attribute__((address_space(3))) void*)p;
}

// ---------------- elementwise fp32 -> bf16 ----------------
__global__ void convert_f32_bf16(const float* __restrict__ in, short* __restrict__ out, int n) {
    int tid = blockIdx.x * blockDim.x + threadIdx.x;
    int stride = gridDim.x * blockDim.x;
    for (int i = tid * 4; i < n; i += stride * 4) {
        float4v v = *(const float4v*)&in[i];
        short4v o;
        o[0] = f2bs(v[0]); o[1] = f2bs(v[1]); o[2] = f2bs(v[2]); o[3] = f2bs(v[3]);
        *(short4v*)&out[i] = o;
    }
}

// ---------------- tiled transpose + convert ----------------
__global__ void transpose_convert(const float* __restrict__ in, short* __restrict__ out,
                                  int rows, int cols) {
    __shared__ float t[32][33];
    int bx = blockIdx.x * 32;
    int by = blockIdx.y * 32;
    int tx = threadIdx.x, ty = threadIdx.y;  // (32, 8)
#pragma unroll
    for (int i = 0; i < 4; ++i)
        t[ty + i * 8][tx] = in[(size_t)(by + ty + i * 8) * cols + bx + tx];
    __syncthreads();
#pragma unroll
    for (int i = 0; i < 4; ++i)
        out[(size_t)(bx + ty + i * 8) * rows + by + tx] = f2bs(t[tx][ty + i * 8]);
}

// ================= 256x256 8-phase GEMM (QKV) =================
#define MFMA16(Q) \
    _Pragma("unroll") for (int mf = 0; mf < 2; ++mf) \
    _Pragma("unroll") for (int nf = 0; nf < 4; ++nf) { \
        acc[(Q)*2+mf][nf] = __builtin_amdgcn_mfma_f32_16x16x32_bf16(af[mf][0], bfrag[nf][0], acc[(Q)*2+mf][nf], 0, 0, 0); \
        acc[(Q)*2+mf][nf] = __builtin_amdgcn_mfma_f32_16x16x32_bf16(af[mf][1], bfrag[nf][1], acc[(Q)*2+mf][nf], 0, 0, 0); \
    }

#define PHASE(Q, STAGE_STMT, WAITV) do { \
    bf16x8 af[2][2]; \
    _Pragma("unroll") for (int mf = 0; mf < 2; ++mf) \
    _Pragma("unroll") for (int ks = 0; ks < 2; ++ks) { \
        int r = (Q)*32 + mf*16 + li; \
        af[mf][ks] = *(const bf16x8*)(lA + r*128 + ((ks*64 + g*16) ^ ((r & 7) << 4))); \
    } \
    STAGE_STMT; \
    __builtin_amdgcn_s_barrier(); \
    asm volatile("s_waitcnt lgkmcnt(0)" ::: "memory"); \
    __builtin_amdgcn_sched_barrier(0); \
    __builtin_amdgcn_s_setprio(1); \
    MFMA16(Q); \
    __builtin_amdgcn_s_setprio(0); \
    WAITV; \
    __builtin_amdgcn_s_barrier(); \
} while (0)

#define VMW(n) asm volatile("s_waitcnt vmcnt(" #n ")" ::: "memory")
#define NOP_ ((void)0)

__global__ __launch_bounds__(512, 2) void gemm256_qkv(
    const short* __restrict__ A, const short* __restrict__ Bt,
    const float* __restrict__ bias,
    short* __restrict__ Qb, short* __restrict__ Kb, short* __restrict__ Vt) {
    __shared__ __attribute__((aligned(16))) short lds[2][2][2][8192];  // [buf][A/B][half][128x64]
    const int tid = threadIdx.x;
    const int lane = tid & 63;
    const int wid = tid >> 6;
    const int li = lane & 15, g = lane >> 4;
    const int wr = wid >> 2, wc = wid & 3;
    const int Kdim = E_;       // 1024
    const int NT = Kdim >> 6;  // 16 K-tiles

    // bijective XCD swizzle: nwg=384, 384/8=48
    const int id = blockIdx.x;
    const int swz = (id & 7) * 48 + (id >> 3);
    const int bx = swz % 12, by = swz / 12;
    const int row0 = by * 256, col0 = bx * 256;

    // staging lane geometry: linear LDS dest, inverse-swizzled global src.
    const int rstage = wid * 8 + (lane >> 3);
    const int cstage = (((lane & 7) ^ ((lane >> 3) & 7)) << 4);

    auto stageA = [&](int buf, int kt, int seg) {
#pragma unroll
        for (int h = 0; h < 2; ++h) {
            const char* src = (const char*)A +
                ((size_t)(row0 + h * 128 + seg * 64 + rstage) * Kdim + kt * 64) * 2 + cstage;
            char* dst = (char*)&lds[buf][0][h][0] + seg * 8192 + wid * 1024;
            __builtin_amdgcn_global_load_lds(gas(src), las(dst), 16, 0, 0);
        }
    };
    auto stageB = [&](int buf, int kt, int h) {
#pragma unroll
        for (int seg = 0; seg < 2; ++seg) {
            const char* src = (const char*)Bt +
                ((size_t)(col0 + h * 128 + seg * 64 + rstage) * Kdim + kt * 64) * 2 + cstage;
            char* dst = (char*)&lds[buf][1][h][0] + seg * 8192 + wid * 1024;
            __builtin_amdgcn_global_load_lds(gas(src), las(dst), 16, 0, 0);
        }
    };

    f32x4 acc[8][4];
#pragma unroll
    for (int m = 0; m < 8; ++m)
#pragma unroll
        for (int n = 0; n < 4; ++n) acc[m][n] = (f32x4){0.f, 0.f, 0.f, 0.f};

    stageB(0, 0, 0);
    stageB(0, 0, 1);
    stageA(0, 0, 0);
    stageA(0, 0, 1);
    asm volatile("s_waitcnt vmcnt(0)" ::: "memory");
    __syncthreads();

    const int bc = (wc & 1) * 64;
    for (int t = 0; t < NT; ++t) {
        const int cur = t & 1;
        const int nb = cur ^ 1;
        const int tn = t + 1;
        const bool st = (tn < NT);
        const char* lA = (const char*)&lds[cur][0][wr][0];
        const char* lB = (const char*)&lds[cur][1][wc >> 1][0];

        bf16x8 bfrag[4][2];
#pragma unroll
        for (int nf = 0; nf < 4; ++nf)
#pragma unroll
            for (int ks = 0; ks < 2; ++ks) {
                int r = bc + nf * 16 + li;
                bfrag[nf][ks] = *(const bf16x8*)(lB + r * 128 + ((ks * 64 + g * 16) ^ ((r & 7) << 4)));
            }
        if (st) {
            PHASE(0, stageB(nb, tn, 0), NOP_);
            PHASE(1, stageB(nb, tn, 1), VMW(4));
            PHASE(2, stageA(nb, tn, 0), NOP_);
            PHASE(3, stageA(nb, tn, 1), VMW(2));
        } else {
            PHASE(0, NOP_, NOP_);
            PHASE(1, NOP_, VMW(0));
            PHASE(2, NOP_, NOP_);
            PHASE(3, NOP_, NOP_);
        }
    }

    // ---- epilogue (C layout: col = lane&15, row = (lane>>4)*4 + j) ----
    if (col0 < 2048) {
        short* Dst = (col0 < 1024) ? Qb : Kb;
#pragma unroll
        for (int nf = 0; nf < 4; ++nf) {
            int ncolg = col0 + wc * 64 + nf * 16 + li;
            float bv = bias[ncolg];
            int ncol = ncolg & 1023;
#pragma unroll
            for (int mi = 0; mi < 8; ++mi) {
                int rbase = row0 + wr * 128 + mi * 16 + 4 * g;
#pragma unroll
                for (int j = 0; j < 4; ++j)
                    Dst[(size_t)(rbase + j) * E_ + ncol] = f2bs(acc[mi][nf][j] + bv);
            }
        }
    } else {
#pragma unroll
        for (int nf = 0; nf < 4; ++nf) {
            int ncolg = col0 + wc * 64 + nf * 16 + li;
            float bv = bias[ncolg];
            int rem = ncolg & 1023;
            int h = rem >> 6, d = rem & 63;
#pragma unroll
            for (int mi = 0; mi < 8; ++mi) {
                int s0 = row0 + wr * 128 + mi * 16 + 4 * g;
                int bb2 = s0 >> 11;
                int ss = s0 & 2047;
                uint2v p;
                p[0] = cvtpk(acc[mi][nf][0] + bv, acc[mi][nf][1] + bv);
                p[1] = cvtpk(acc[mi][nf][2] + bv, acc[mi][nf][3] + bv);
                *(uint2v*)&Vt[((size_t)(bb2 * H_ + h) * D_ + d) * S_ + ss] = p;
            }
        }
    }
}

// ---------------- bf16 GEMM, 128x128 tile (out-proj) ----------------
__global__ __launch_bounds__(256, 2) void gemm_bt_out(
    const short* __restrict__ A, const short* __restrict__ Bt,
    const float* __restrict__ bias, float* __restrict__ Cf,
    int Kdim, int Ndim) {
    __shared__ __attribute__((aligned(16))) short As[128 * 32];
    __shared__ __attribute__((aligned(16))) short Bs[128 * 32];
    const int lane = threadIdx.x & 63;
    const int wv = threadIdx.x >> 6;
    const int row0 = blockIdx.y * 128;
    const int col0 = blockIdx.x * 128;
    const int wr = (wv >> 1) * 64;
    const int wc = (wv & 1) * 64;
    const int li = lane & 15;
    const int g = lane >> 4;
    const int lr = lane >> 2;
    const int lk = (lane & 3) * 8;

    f32x4 acc[4][4];
#pragma unroll
    for (int m = 0; m < 4; ++m)
#pragma unroll
        for (int n = 0; n < 4; ++n) acc[m][n] = (f32x4){0.f, 0.f, 0.f, 0.f};

    for (int k0 = 0; k0 < Kdim; k0 += 32) {
#pragma unroll
        for (int i = 0; i < 2; ++i) {
            int cc = wv * 2 + i;
            const short* ga = A + (size_t)(row0 + cc * 16 + lr) * Kdim + k0 + lk;
            __builtin_amdgcn_global_load_lds(gas(ga), las(&As[cc * 512]), 16, 0, 0);
            const short* gb = Bt + (size_t)(col0 + cc * 16 + lr) * Kdim + k0 + lk;
            __builtin_amdgcn_global_load_lds(gas(gb), las(&Bs[cc * 512]), 16, 0, 0);
        }
        __syncthreads();
        bf16x8 af[4], bfr[4];
#pragma unroll
        for (int m = 0; m < 4; ++m) af[m] = *(const bf16x8*)&As[(wr + 16 * m + li) * 32 + g * 8];
#pragma unroll
        for (int n = 0; n < 4; ++n) bfr[n] = *(const bf16x8*)&Bs[(wc + 16 * n + li) * 32 + g * 8];
#pragma unroll
        for (int m = 0; m < 4; ++m)
#pragma unroll
            for (int n = 0; n < 4; ++n)
                acc[m][n] = __builtin_amdgcn_mfma_f32_16x16x32_bf16(af[m], bfr[n], acc[m][n], 0, 0, 0);
        __syncthreads();
    }

#pragma unroll
    for (int n = 0; n < 4; ++n) {
        int ncol = col0 + wc + 16 * n + li;
        float bv = bias[ncol];
#pragma unroll
        for (int m = 0; m < 4; ++m) {
            int rbase = row0 + wr + 16 * m + 4 * g;
#pragma unroll
            for (int j = 0; j < 4; ++j)
                Cf[(size_t)(rbase + j) * Ndim + ncol] = acc[m][n][j] + bv;
        }
    }
}

// ---------------- causal flash attention v7b: merged 64-key softmax (mask fixed) ----------------
// 256 threads = 4 waves x 32 q-rows. Grid 1024 (xcd-pinned, heavy-first).
// Per 64-key tile: 8 QK mfma (2 indep chains) -> ONE 31-op max tree + 1 shfl ->
// defer-max rescale (THR=16 logits) -> 32 exp2 in place -> one l-reduce ->
// pack both subtiles -> 8 PV mfma (2 chains of 4).
// Mask predicate: needed iff max key (kt0+63) > min q (q0w).  [R9 bug: used q0w+31]
__global__ __launch_bounds__(256, 4) void attn_kernel(
    const short* __restrict__ Qb, const short* __restrict__ Kb,
    const short* __restrict__ Vt, short* __restrict__ Ob) {
    __shared__ __attribute__((aligned(16))) short Kl[4096];  // [64 keys][64 d] 8KB
    __shared__ __attribute__((aligned(16))) short Vl[4096];  // [64 d][64 keys] 8KB
    const int lane = threadIdx.x & 63;
    const int wv = threadIdx.x >> 6;          // 0..3
    const int l31 = lane & 31;
    const int hi = lane >> 5;                 // 0/1
    const int id = blockIdx.x;
    const int xcd = id & 7;
    const int r_ = id >> 3;                   // 0..127
    const int qt = 15 - (r_ >> 3);            // 15..0 heavy-first
    const int bh = xcd * 8 + (r_ & 7);
    const int bb = bh >> 4, hh = bh & 15;
    const short* Qh = Qb + (size_t)bb * (S_ * E_) + hh * 64;
    const short* Kh = Kb + (size_t)bb * (S_ * E_) + hh * 64;
    const short* Vh = Vt + (size_t)bh * (D_ * S_);
    const float CEXP = 0.18033688011112042f;  // (1/8)*log2(e)

    const int rstage = wv * 8 + (lane >> 3);                      // 0..31
    const int cstage = (((lane & 7) ^ ((lane >> 3) & 7)) << 4);   // inverse swizzle

    const int q0w = qt * 128 + wv * 32;
    const int q = q0w + l31;  // this lane's q-row

    bf16x8 qf[4];
#pragma unroll
    for (int c = 0; c < 4; ++c)
        qf[c] = *(const bf16x8*)&Qh[(size_t)q * E_ + c * 16 + hi * 8];

    f32x16 acc[2];
#pragma unroll
    for (int d = 0; d < 2; ++d)
#pragma unroll
        for (int r = 0; r < 16; ++r) acc[d][r] = 0.f;
    float m = -3e38f, mC = 0.f, l = 0.f;

    const int nw = (q0w + 95) >> 6;          // 64-key tiles this wave computes
    const int nt = (qt * 128 + 191) >> 6;    // tiles staged by block

    for (int it = 0; it < nt; ++it) {
        const int kt0 = it * 64;
#pragma unroll
        for (int half = 0; half < 2; ++half) {
            const char* gk = (const char*)(Kh + (size_t)(kt0 + half * 32 + rstage) * E_) + cstage;
            __builtin_amdgcn_global_load_lds(gas(gk), las((char*)Kl + half * 4096 + wv * 1024), 16, 0, 0);
            const char* gv = (const char*)Vh + (size_t)(half * 32 + rstage) * (S_ * 2) + (size_t)kt0 * 2 + cstage;
            __builtin_amdgcn_global_load_lds(gas(gv), las((char*)Vl + half * 4096 + wv * 1024), 16, 0, 0);
        }
        __syncthreads();
        if (it < nw) {
            // ---- QK^T both subtiles (swapped): S[key][q] ----
            f32x16 sc0, sc1;
#pragma unroll
            for (int r = 0; r < 16; ++r) { sc0[r] = 0.f; sc1[r] = 0.f; }
#pragma unroll
            for (int c = 0; c < 4; ++c) {
                const int r0 = l31, r1 = 32 + l31;
                bf16x8 kf0 = *(const bf16x8*)((const char*)Kl + r0 * 128 +
                                              ((c * 32 + hi * 16) ^ ((r0 & 7) << 4)));
                bf16x8 kf1 = *(const bf16x8*)((const char*)Kl + r1 * 128 +
                                              ((c * 32 + hi * 16) ^ ((r1 & 7) << 4)));
                sc0 = __builtin_amdgcn_mfma_f32_32x32x16_bf16(kf0, qf[c], sc0, 0, 0, 0);
                sc1 = __builtin_amdgcn_mfma_f32_32x32x16_bf16(kf1, qf[c], sc1, 0, 0, 0);
            }
            // ---- causal mask: needed iff max key (kt0+63) > min q (q0w) ----
            if (kt0 + 63 > q0w) {
                const int kb = kt0 + 4 * hi;
#pragma unroll
                for (int r = 0; r < 16; ++r) {
                    int key = kb + (r & 3) + 8 * (r >> 2);
                    sc0[r] = (key > q) ? -3e38f : sc0[r];
                    sc1[r] = (key + 32 > q) ? -3e38f : sc1[r];
                }
            }
            // ---- row max over all 64 keys: 31-op tree + 1 shfl ----
            float tmx[8];
#pragma unroll
            for (int r = 0; r < 8; ++r)
                tmx[r] = fmaxf(fmaxf(sc0[2 * r], sc0[2 * r + 1]),
                               fmaxf(sc1[2 * r], sc1[2 * r + 1]));
            float tm = fmaxf(fmaxf(fmaxf(tmx[0], tmx[1]), fmaxf(tmx[2], tmx[3])),
                             fmaxf(fmaxf(tmx[4], tmx[5]), fmaxf(tmx[6], tmx[7])));
            tm = fmaxf(tm, __shfl_xor(tm, 32, 64));
            // ---- defer-max: rescale only if max grew > THR (16 logit units) ----
            bool need = (tm > m + 16.0f);
            if (__ballot((int)need) != 0ull) {
                float mn = fmaxf(m, tm);
                float sf = exp2a((m - mn) * CEXP);
                m = mn; mC = mn * CEXP;
                l *= sf;
#pragma unroll
                for (int d = 0; d < 2; ++d)
#pragma unroll
                    for (int r = 0; r < 16; ++r) acc[d][r] *= sf;
            }
            // ---- p = exp2(s*C - m*C) in place ----
#pragma unroll
            for (int r = 0; r < 16; ++r) {
                sc0[r] = exp2a(fmaf(sc0[r], CEXP, -mC));
                sc1[r] = exp2a(fmaf(sc1[r], CEXP, -mC));
            }
            // ---- one l-reduce over 32 values ----
            float s0 = 0.f, s1 = 0.f;
#pragma unroll
            for (int r = 0; r < 8; ++r) {
                s0 += sc0[2 * r] + sc0[2 * r + 1];
                s1 += sc1[2 * r] + sc1[2 * r + 1];
            }
            float ls = s0 + s1;
            ls += __shfl_xor(ls, 32, 64);
            l += ls;
            // ---- pack both subtiles -> 4 PV B-frags ----
            const bool lo = (hi == 0);
            bf16x8 pf[4];
#pragma unroll
            for (int s = 0; s < 2; ++s) {
                const f32x16& p = s ? sc1 : sc0;
                unsigned W0 = cvtpk(p[0], p[1]),   W1 = cvtpk(p[2], p[3]);
                unsigned W2 = cvtpk(p[4], p[5]),   W3 = cvtpk(p[6], p[7]);
                unsigned W4 = cvtpk(p[8], p[9]),   W5 = cvtpk(p[10], p[11]);
                unsigned W6 = cvtpk(p[12], p[13]), W7 = cvtpk(p[14], p[15]);
                unsigned xW0 = __shfl_xor(W0, 32, 64), xW1 = __shfl_xor(W1, 32, 64);
                unsigned xW2 = __shfl_xor(W2, 32, 64), xW3 = __shfl_xor(W3, 32, 64);
                unsigned xW4 = __shfl_xor(W4, 32, 64), xW5 = __shfl_xor(W5, 32, 64);
                unsigned xW6 = __shfl_xor(W6, 32, 64), xW7 = __shfl_xor(W7, 32, 64);
                uint4v u1, u2;
                u1[0] = lo ? W0 : xW2;  u1[1] = lo ? W1 : xW3;
                u1[2] = lo ? xW0 : W2;  u1[3] = lo ? xW1 : W3;
                u2[0] = lo ? W4 : xW6;  u2[1] = lo ? W5 : xW7;
                u2[2] = lo ? xW4 : W6;  u2[3] = lo ? xW5 : W7;
                pf[s * 2] = __builtin_bit_cast(bf16x8, u1);
                pf[s * 2 + 1] = __builtin_bit_cast(bf16x8, u2);
            }
            // ---- PV: acc[db] += V^T-frags x P-frags (4 chained K=16 each) ----
#pragma unroll
            for (int db = 0; db < 2; ++db) {
                const int row = db * 32 + l31;
                const int rsw = (row & 7) << 4;
                const char* vrow = (const char*)Vl + row * 128;
                bf16x8 v0 = *(const bf16x8*)(vrow + ((hi * 16) ^ rsw));
                bf16x8 v1 = *(const bf16x8*)(vrow + ((32 + hi * 16) ^ rsw));
                bf16x8 v2 = *(const bf16x8*)(vrow + ((64 + hi * 16) ^ rsw));
                bf16x8 v3 = *(const bf16x8*)(vrow + ((96 + hi * 16) ^ rsw));
                acc[db] = __builtin_amdgcn_mfma_f32_32x32x16_bf16(v0, pf[0], acc[db], 0, 0, 0);
                acc[db] = __builtin_amdgcn_mfma_f32_32x32x16_bf16(v1, pf[1], acc[db], 0, 0, 0);
                acc[db] = __builtin_amdgcn_mfma_f32_32x32x16_bf16(v2, pf[2], acc[db], 0, 0, 0);
                acc[db] = __builtin_amdgcn_mfma_f32_32x32x16_bf16(v3, pf[3], acc[db], 0, 0, 0);
            }
        }
        __syncthreads();
    }

    // ---- epilogue: O[q][d] = acc^T / l ; 8B packed stores ----
    float rl = __builtin_amdgcn_rcpf(l);
    short* orow = Ob + ((size_t)(bb * S_ + q)) * E_ + hh * 64;
#pragma unroll
    for (int db = 0; db < 2; ++db)
#pragma unroll
        for (int rb = 0; rb < 4; ++rb) {
            uint2v pk;
            pk[0] = cvtpk(acc[db][rb * 4 + 0] * rl, acc[db][rb * 4 + 1] * rl);
            pk[1] = cvtpk(acc[db][rb * 4 + 2] * rl, acc[db][rb * 4 + 3] * rl);
            *(uint2v*)&orow[db * 32 + rb * 8 + hi * 4] = pk;
        }
}

extern "C" void kernel_launch(void* const* d_in, const int* in_sizes, int n_in,
                              void* d_out, int out_size, void* d_ws, size_t ws_size,
                              hipStream_t stream) {
    const float* x      = (const float*)d_in[0];
    const float* w_attn = (const float*)d_in[1];
    const float* b_attn = (const float*)d_in[2];
    const float* w_out  = (const float*)d_in[3];
    const float* b_out  = (const float*)d_in[4];
    float* out = (float*)d_out;

    char* ws = (char*)d_ws;
    short* Xbf  = (short*)(ws);                       // 16 MB (reused as attn output)
    short* Wat  = (short*)(ws + (16ull << 20));       // 6 MB  [3072][1024]
    short* Wot  = (short*)(ws + (22ull << 20));       // 2 MB  [1024][1024]
    short* Qb   = (short*)(ws + (24ull << 20));       // 16 MB flat [8192][1024]
    short* Kb   = (short*)(ws + (40ull << 20));       // 16 MB flat [8192][1024]
    short* Vt   = (short*)(ws + (56ull << 20));       // 16 MB [B,H,D,S]
    short* Obuf = Xbf;

    convert_f32_bf16<<<2048, 256, 0, stream>>>(x, Xbf, M_ * E_);
    transpose_convert<<<dim3(N1_ / 32, E_ / 32), dim3(32, 8), 0, stream>>>(w_attn, Wat, E_, N1_);
    transpose_convert<<<dim3(E_ / 32, E_ / 32), dim3(32, 8), 0, stream>>>(w_out, Wot, E_, E_);

    gemm256_qkv<<<384, 512, 0, stream>>>(Xbf, Wat, b_attn, Qb, Kb, Vt);

    attn_kernel<<<1024, 256, 0, stream>>>(Qb, Kb, Vt, Obuf);

    gemm_bt_out<<<dim3(E_ / 128, M_ / 128), 256, 0, stream>>>(
        Obuf, Wot, b_out, out, E_, E_);
}